// Round 1
// baseline (302.353 us; speedup 1.0000x reference)
//
#include <hip/hip_runtime.h>

// SheafLaplacianBuilder on gfx950.
// n=1024 nodes, E=32768 directed edges, d=8. Output: dense (n*d, n*d) fp32.
// Strategy: memset output (256 MB, the BW floor), then scatter 8x8 blocks.
// D_v^{-1/2} computed via coupled Newton-Schulz inverse-sqrt (replaces eigh;
// eigenvalues ~23 +/- 8 so lambda/trace >= ~0.05 -> converges in <10 iters).

#define NS_ITERS 18

// ---------------------------------------------------------------------------
// Kernel A: per-edge ftf = F^T F, atomicAdd into diag[src[e]] (n,8,8).
// 64 threads per edge, 4 edges per 256-thread block. E divisible by 4.
__global__ __launch_bounds__(256) void ftf_diag_kernel(
    const float* __restrict__ maps, const int* __restrict__ src,
    float* __restrict__ diag) {
  __shared__ float M[4][64];
  const int g = threadIdx.x >> 6, t = threadIdx.x & 63;
  const int i = t >> 3, j = t & 7;
  const int e = blockIdx.x * 4 + g;
  M[g][t] = maps[(size_t)e * 64 + t];
  __syncthreads();
  float f = 0.f;
#pragma unroll
  for (int k = 0; k < 8; ++k) f += M[g][k * 8 + i] * M[g][k * 8 + j];
  atomicAdd(&diag[(size_t)src[e] * 64 + t], f);
}

// ---------------------------------------------------------------------------
// Kernel B: per-node D_v^{-1/2} via coupled Newton-Schulz.
// Y0 = A/c (c = trace), Z0 = I;  T = Z*Y, W = (3I - T)/2, Y<-Y*W, Z<-W*Z.
// Z -> (A/c)^{-1/2}, so A^{-1/2} = Z / sqrt(c).
// 64 threads per node (one per matrix element), 4 nodes per block.
__global__ __launch_bounds__(256) void dinv_kernel(
    const float* __restrict__ diag, float* __restrict__ dinv) {
  __shared__ float Y[4][64], Z[4][64], W[4][64];
  const int g = threadIdx.x >> 6, t = threadIdx.x & 63;
  const int i = t >> 3, j = t & 7;
  const int v = blockIdx.x * 4 + g;
  const float a = diag[(size_t)v * 64 + t] + ((i == j) ? 1e-5f : 0.f);
  Y[g][t] = a;
  __syncthreads();
  float c = 0.f;
#pragma unroll
  for (int k = 0; k < 8; ++k) c += Y[g][k * 8 + k];  // trace (broadcast reads)
  const float rc = 1.f / c;
  __syncthreads();  // all trace reads done before overwrite
  Y[g][t] = a * rc;
  Z[g][t] = (i == j) ? 1.f : 0.f;
  __syncthreads();
  for (int it = 0; it < NS_ITERS; ++it) {
    float tr = 0.f;
#pragma unroll
    for (int k = 0; k < 8; ++k) tr += Z[g][i * 8 + k] * Y[g][k * 8 + j];
    const float w = 0.5f * (((i == j) ? 3.f : 0.f) - tr);
    W[g][t] = w;  // W not read until after next barrier; no hazard with Y/Z reads
    __syncthreads();
    float yn = 0.f, zn = 0.f;
#pragma unroll
    for (int k = 0; k < 8; ++k) {
      yn += Y[g][i * 8 + k] * W[g][k * 8 + j];
      zn += W[g][i * 8 + k] * Z[g][k * 8 + j];
    }
    __syncthreads();
    Y[g][t] = yn;
    Z[g][t] = zn;
    __syncthreads();
  }
  dinv[(size_t)v * 64 + t] = Z[g][t] * rsqrtf(c);
}

// ---------------------------------------------------------------------------
// Kernel C: diagonal blocks. out block (v,v) = Dinv_v @ diag_v @ Dinv_v.
__global__ __launch_bounds__(256) void diag_block_kernel(
    const float* __restrict__ diag, const float* __restrict__ dinv,
    float* __restrict__ out, int n) {
  __shared__ float A[4][64], Dn[4][64], T[4][64];
  const int g = threadIdx.x >> 6, t = threadIdx.x & 63;
  const int i = t >> 3, j = t & 7;
  const int v = blockIdx.x * 4 + g;
  A[g][t] = diag[(size_t)v * 64 + t];
  Dn[g][t] = dinv[(size_t)v * 64 + t];
  __syncthreads();
  float s = 0.f;
#pragma unroll
  for (int k = 0; k < 8; ++k) s += A[g][i * 8 + k] * Dn[g][k * 8 + j];
  T[g][t] = s;
  __syncthreads();
  float b = 0.f;
#pragma unroll
  for (int k = 0; k < 8; ++k) b += Dn[g][i * 8 + k] * T[g][k * 8 + j];
  const size_t nd = (size_t)n * 8;
  out[((size_t)v * 8 + i) * nd + (size_t)v * 8 + j] = b;
}

// ---------------------------------------------------------------------------
// Kernel D: off-diagonal blocks. off = -F_rev^T @ F_e;
// out block (src,dst) = Dinv_src @ off @ Dinv_dst.  (edge pairs unique)
__global__ __launch_bounds__(256) void off_block_kernel(
    const float* __restrict__ maps, const int* __restrict__ src,
    const int* __restrict__ dst, const int* __restrict__ rev,
    const float* __restrict__ dinv, float* __restrict__ out, int n) {
  __shared__ float M[4][64], R[4][64], Du[4][64], Dv[4][64];
  const int g = threadIdx.x >> 6, t = threadIdx.x & 63;
  const int i = t >> 3, j = t & 7;
  const int e = blockIdx.x * 4 + g;
  const int v = src[e], u = dst[e], r = rev[e];
  M[g][t] = maps[(size_t)e * 64 + t];
  R[g][t] = maps[(size_t)r * 64 + t];
  Du[g][t] = dinv[(size_t)u * 64 + t];
  Dv[g][t] = dinv[(size_t)v * 64 + t];
  __syncthreads();
  // off[i][j] = -sum_k R[k][i] * M[k][j]
  float o = 0.f;
#pragma unroll
  for (int k = 0; k < 8; ++k) o += R[g][k * 8 + i] * M[g][k * 8 + j];
  o = -o;
  __syncthreads();
  M[g][t] = o;  // M := off
  __syncthreads();
  float t1 = 0.f;
#pragma unroll
  for (int k = 0; k < 8; ++k) t1 += M[g][i * 8 + k] * Du[g][k * 8 + j];
  __syncthreads();
  R[g][t] = t1;  // R := off @ Dinv_u
  __syncthreads();
  float b = 0.f;
#pragma unroll
  for (int k = 0; k < 8; ++k) b += Dv[g][i * 8 + k] * R[g][k * 8 + j];
  const size_t nd = (size_t)n * 8;
  out[((size_t)v * 8 + i) * nd + (size_t)u * 8 + j] = b;
}

// ---------------------------------------------------------------------------
extern "C" void kernel_launch(void* const* d_in, const int* in_sizes, int n_in,
                              void* d_out, int out_size, void* d_ws,
                              size_t ws_size, hipStream_t stream) {
  const float* maps = (const float*)d_in[0];
  const int* src = (const int*)d_in[1];
  const int* dst = (const int*)d_in[2];
  const int* rev = (const int*)d_in[3];
  float* out = (float*)d_out;

  const int E = in_sizes[1];   // 32768
  const int n = E / 32;        // 2*DEG directed edges per node, DEG=16 -> 1024

  float* diag = (float*)d_ws;                 // n*64 floats
  float* dinv = diag + (size_t)n * 64;        // n*64 floats

  // Zero the dense output (the dominant cost: 256 MB of HBM writes) and the
  // diag accumulator (harness re-poisons ws with 0xAA before every call).
  hipMemsetAsync(d_out, 0, (size_t)out_size * sizeof(float), stream);
  hipMemsetAsync(diag, 0, (size_t)n * 64 * sizeof(float), stream);

  ftf_diag_kernel<<<E / 4, 256, 0, stream>>>(maps, src, diag);
  dinv_kernel<<<n / 4, 256, 0, stream>>>(diag, dinv);
  diag_block_kernel<<<n / 4, 256, 0, stream>>>(diag, dinv, out, n);
  off_block_kernel<<<E / 4, 256, 0, stream>>>(maps, src, dst, rev, dinv, out, n);
}